// Round 17
// baseline (335.883 us; speedup 1.0000x reference)
//
#include <hip/hip_runtime.h>
#include <hip/hip_bf16.h>
#include <hip/hip_fp16.h>

typedef _Float16 f16;
typedef _Float16 f16x2 __attribute__((ext_vector_type(2)));
typedef _Float16 f16x4 __attribute__((ext_vector_type(4)));
typedef _Float16 f16x8 __attribute__((ext_vector_type(8)));
typedef float f32x4 __attribute__((ext_vector_type(4)));

typedef __attribute__((address_space(1))) const void gas_t;
typedef __attribute__((address_space(3))) void las_t;

#define BN_EPS 1e-5f

// ---------------- kernel 1: graph start offsets from sorted segment_ids ----------------
__global__ void seg_starts_k(const int* __restrict__ seg, int N, int G, int* __restrict__ start) {
    int n = blockIdx.x * blockDim.x + threadIdx.x;
    if (n >= N) return;
    int s = seg[n];
    int p = (n == 0) ? -1 : seg[n - 1];
    for (int g = p + 1; g <= s; ++g) start[g] = n;
    if (n == N - 1) {
        for (int g = s + 1; g <= G; ++g) start[g] = N;
    }
}

// ---------------- kernel 2: weight prep (BN folding, fp16, PRE-SWIZZLED) ----------------
__global__ void prep_k(const float* __restrict__ W1, const float* __restrict__ b1,
                       const float* __restrict__ W2, const float* __restrict__ b2,
                       const float* __restrict__ W3, const float* __restrict__ b3,
                       const float* __restrict__ oW1, const float* __restrict__ ob1,
                       const float* __restrict__ g1, const float* __restrict__ be1,
                       const float* __restrict__ rm1, const float* __restrict__ rv1,
                       const float* __restrict__ g2, const float* __restrict__ be2,
                       const float* __restrict__ rm2, const float* __restrict__ rv2,
                       const float* __restrict__ g3, const float* __restrict__ be3,
                       const float* __restrict__ rm3, const float* __restrict__ rv3,
                       f16* __restrict__ Wt, float* __restrict__ bp) {
    int T = gridDim.x;
    int t = blockIdx.x, l = blockIdx.y;
    int o = threadIdx.x;  // 0..127
    __shared__ float s_sh[128], c_sh[128];

    const float *W, *b, *gg = nullptr, *be = nullptr, *rm = nullptr, *rv = nullptr;
    if (l == 0)      { W = W1;  b = b1; }
    else if (l == 1) { W = W2;  b = b2;  gg = g1; be = be1; rm = rm1; rv = rv1; }
    else if (l == 2) { W = W3;  b = b3;  gg = g2; be = be2; rm = rm2; rv = rv2; }
    else             { W = oW1; b = ob1; gg = g3; be = be3; rm = rm3; rv = rv3; }

    float s = 1.f, c = 0.f;
    if (gg) {
        float sv = gg[t * 128 + o] * rsqrtf(rv[t * 128 + o] + BN_EPS);
        s = sv;
        c = be[t * 128 + o] - rm[t * 128 + o] * sv;
    }
    s_sh[o] = s;
    c_sh[o] = c;
    __syncthreads();

    const float* Wsrc = W + (size_t)t * 128 * 128;
    f16* Wdst = Wt + (((size_t)l * T + t) * 128 + o) * 128;  // row o, swizzled cols
    float acc = b[t * 128 + o];
    for (int i = 0; i < 128; ++i) {
        float wv = Wsrc[i * 128 + o];
        Wdst[(((i >> 3) ^ (o & 7)) << 3) + (i & 7)] = (f16)(s_sh[i] * wv);
        acc += c_sh[i] * wv;
    }
    bp[((size_t)l * T + t) * 128 + o] = acc;
}

// ---------------- kernel 3: zero-LDS pooling, bx prefetch + LDS-bounce stores (pool5c) ----------------
// vs r16: next chunk's 32 bx dword loads issued BEFORE the current chunk's
// compute (HBM latency hides under w-MFMA/sigmoid/pool-MFMA). Both bx sets
// f16-packed (f16x4 bxh[8] = 16 VGPR each) to cap register pressure.
__global__ __launch_bounds__(256) void pool5_k(const float* __restrict__ feats,
                                               const float* __restrict__ atom_w,
                                               const float* __restrict__ atom_b,
                                               const int* __restrict__ start,
                                               f16* __restrict__ mol, int G) {
    __shared__ f16 wls_all[4][12][128];   // 3KB per wave, wave-private
    int wave = threadIdx.x >> 6, lane = threadIdx.x & 63;
    int g = blockIdx.x * 4 + wave;
    if (g >= G) return;
    int lr = lane & 15, kg = lane >> 4;
    f16 (*wls)[128] = wls_all[wave];

    f16x8 bfr[4];
    float ab = 0.f;
#pragma unroll
    for (int ks = 0; ks < 4; ++ks) {
        f16x8 v = {};
        if (lr < 12) {
            const float* s = atom_w + lr * 128 + ks * 32 + kg * 8;
#pragma unroll
            for (int j = 0; j < 8; ++j) v[j] = (f16)s[j];
        }
        bfr[ks] = v;
    }
    if (lr < 12) ab = atom_b[lr];

    f32x4 acc[8];
#pragma unroll
    for (int nf = 0; nf < 8; ++nf) acc[nf] = (f32x4){0.f, 0.f, 0.f, 0.f};

    int s = start[g], e = start[g + 1];

    // bx loader: chunk at c0 -> 32 dwords, f16-packed per fb
    auto load_bx = [&](int c0, f16x4* dst) {
#pragma unroll
        for (int j = 0; j < 4; ++j) {
            int a = c0 + (kg << 2) + j;
            int r = (a < e) ? a : (e - 1);
            const float* pB = feats + (size_t)r * 128 + lr;
#pragma unroll
            for (int fb = 0; fb < 8; ++fb) dst[fb][j] = (f16)pB[fb << 4];
        }
    };

    f16x4 bxh[8];
    if (s < e) load_bx(s, bxh);

    for (int c0 = s; c0 < e; c0 += 16) {
        bool hasNext = (c0 + 16) < e;
        f16x4 bxh2[8];
        if (hasNext) load_bx(c0 + 16, bxh2);      // prefetch: in flight during compute

        // A-frag row (atom c0+lr, clamped); L1-hot behind current bx lines
        int rA = c0 + lr; if (rA >= e) rA = e - 1;
        const float* pA = feats + (size_t)rA * 128 + (kg << 3);
        f32x4 pa = {0.f, 0.f, 0.f, 0.f};
#pragma unroll
        for (int ks = 0; ks < 4; ++ks) {
            float4 u0 = *(const float4*)(pA + (ks << 5));
            float4 u1 = *(const float4*)(pA + (ks << 5) + 4);
            f16x8 afr;
            afr[0] = (f16)u0.x; afr[1] = (f16)u0.y; afr[2] = (f16)u0.z; afr[3] = (f16)u0.w;
            afr[4] = (f16)u1.x; afr[5] = (f16)u1.y; afr[6] = (f16)u1.z; afr[7] = (f16)u1.w;
            pa = __builtin_amdgcn_mfma_f32_16x16x32_f16(afr, bfr[ks], pa, 0, 0, 0);
        }

        f16x4 a2;
#pragma unroll
        for (int j = 0; j < 4; ++j) {
            float w = 1.f / (1.f + __expf(-(pa[j] + ab)));
            int a = c0 + (kg << 2) + j;
            a2[j] = (a < e) ? (f16)w : (f16)0.f;
        }

#pragma unroll
        for (int fb = 0; fb < 8; ++fb)
            acc[fb] = __builtin_amdgcn_mfma_f32_16x16x16f16(a2, bxh[fb], acc[fb], 0, 0, 0);

        if (hasNext) {
#pragma unroll
            for (int fb = 0; fb < 8; ++fb) bxh[fb] = bxh2[fb];
        }
    }

    // epilogue: LDS bounce (swizzle baked in), then 3 b128 stores per lane
    if (kg < 3) {
        int gx = g & 7;
#pragma unroll
        for (int fb = 0; fb < 8; ++fb) {
            int slot = (fb << 1) + (lr >> 3);
            int fi = (((slot ^ gx)) << 3) + (lr & 7);
#pragma unroll
            for (int j = 0; j < 4; ++j)
                wls[(kg << 2) + j][fi] = (f16)acc[fb][j];
        }
    }
    // wave-private LDS; same-wave DS ordering -> no barrier needed
#pragma unroll
    for (int k = 0; k < 3; ++k) {
        int t = (k << 2) + kg;               // 0..11
        f16x8 v = *(const f16x8*)(&wls[t][lr << 3]);
        *(f16x8*)(mol + ((size_t)t * G + g) * 128 + (lr << 3)) = v;
    }
}

// ---------------- kernel 4: fc v3 — 2x2 wave tiling at 48KB, 3 blocks/CU ----------------
// (byte-identical to round 15/16)
__global__ __launch_bounds__(256, 3) void fc_k(const f16* __restrict__ mol,
                                               const f16* __restrict__ Wt,
                                               const float* __restrict__ bp,
                                               const float* __restrict__ oW2,
                                               const float* __restrict__ ob2,
                                               float* __restrict__ out, int G, int T) {
    __shared__ f16 A[64][128];          // 16KB (aliased as pred scratch at end)
    __shared__ f16 B[128][128];         // 32KB

    int t = blockIdx.y;
    int g0 = blockIdx.x * 64;
    int tid = threadIdx.x;
    int wid = tid >> 6, lane = tid & 63;
    int kg = lane >> 4, lr = lane & 15;
    int wr = wid >> 1, wc = wid & 1;
    int ar0 = wr * 32, bc0 = wc * 64;

    {
        const f16* aplane = mol + (size_t)t * G * 128;
#pragma unroll
        for (int i = 0; i < 4; ++i) {
            int c = wid + (i << 2);                 // chunk 0..15
            int r = (c << 2) + kg;
            int row = g0 + r; if (row >= G) row = G - 1;
            const f16* src = aplane + (size_t)row * 128 + (lr << 3);
            __builtin_amdgcn_global_load_lds((gas_t*)src,
                (las_t*)((char*)&A[0][0] + c * 1024), 16, 0, 0);
        }
        const f16* bsrc = Wt + ((size_t)0 * T + t) * 16384;
#pragma unroll
        for (int i = 0; i < 8; ++i) {
            int c = wid + (i << 2);                 // chunk 0..31
            int r = (c << 2) + kg;
            const f16* src = bsrc + (size_t)r * 128 + (lr << 3);
            __builtin_amdgcn_global_load_lds((gas_t*)src,
                (las_t*)((char*)&B[0][0] + c * 1024), 16, 0, 0);
        }
    }

    float pred[2][4];
#pragma unroll
    for (int m = 0; m < 2; ++m)
#pragma unroll
        for (int j = 0; j < 4; ++j) pred[m][j] = 0.f;

    for (int l = 0; l < 4; ++l) {
        asm volatile("s_waitcnt vmcnt(0)" ::: "memory");   // B(l) (+prologue A) landed
        __syncthreads();                                   // bar1: staging + A(l-1) visible

        f16x8 afr[2][4];
#pragma unroll
        for (int m = 0; m < 2; ++m) {
            int row = ar0 + m * 16 + lr;
#pragma unroll
            for (int ks = 0; ks < 4; ++ks) {
                int sl = (4 * ks + kg) ^ (row & 7);
                afr[m][ks] = *(const f16x8*)(&A[row][sl * 8]);
            }
        }
        __syncthreads();    // bar2: afr reads done before cross-wave A-writeback

        const float* bias = bp + ((size_t)l * T + t) * 128;
#pragma unroll
        for (int n = 0; n < 4; ++n) {
            int col = bc0 + n * 16 + lr;
            f32x4 acc0 = {0.f, 0.f, 0.f, 0.f};
            f32x4 acc1 = {0.f, 0.f, 0.f, 0.f};
#pragma unroll
            for (int ks = 0; ks < 4; ++ks) {
                int sl = (4 * ks + kg) ^ (col & 7);
                f16x8 bfr = *(const f16x8*)(&B[col][sl * 8]);
                acc0 = __builtin_amdgcn_mfma_f32_16x16x32_f16(afr[0][ks], bfr, acc0, 0, 0, 0);
                acc1 = __builtin_amdgcn_mfma_f32_16x16x32_f16(afr[1][ks], bfr, acc1, 0, 0, 0);
            }
            float bv = bias[col];
            if (l < 3) {
#pragma unroll
                for (int j = 0; j < 4; ++j) {
                    float y0 = acc0[j] + bv; y0 = y0 > 0.f ? y0 : 0.f;
                    float y1 = acc1[j] + bv; y1 = y1 > 0.f ? y1 : 0.f;
                    int r0 = ar0 + 4 * kg + j;
                    int r1 = r0 + 16;
                    A[r0][(((col >> 3) ^ (r0 & 7)) << 3) + (col & 7)] = (f16)y0;
                    A[r1][(((col >> 3) ^ (r1 & 7)) << 3) + (col & 7)] = (f16)y1;
                }
            } else {
                float w2 = oW2[t * 128 + col];
#pragma unroll
                for (int j = 0; j < 4; ++j) {
                    float z0 = acc0[j] + bv; z0 = z0 > 0.f ? z0 : 0.f;
                    float z1 = acc1[j] + bv; z1 = z1 > 0.f ? z1 : 0.f;
                    pred[0][j] += z0 * w2;
                    pred[1][j] += z1 * w2;
                }
            }
        }
        __syncthreads();    // bar3: all waves done reading B(l)
        if (l < 3) {
            const f16* bsrc = Wt + ((size_t)(l + 1) * T + t) * 16384;
#pragma unroll
            for (int i = 0; i < 8; ++i) {
                int c = wid + (i << 2);
                int r = (c << 2) + kg;
                const f16* src = bsrc + (size_t)r * 128 + (lr << 3);
                __builtin_amdgcn_global_load_lds((gas_t*)src,
                    (las_t*)((char*)&B[0][0] + c * 1024), 16, 0, 0);
            }
        }
    }

#pragma unroll
    for (int msk = 1; msk < 16; msk <<= 1) {
#pragma unroll
        for (int m = 0; m < 2; ++m)
#pragma unroll
            for (int j = 0; j < 4; ++j)
                pred[m][j] += __shfl_xor(pred[m][j], msk, 64);
    }

    __syncthreads();
    float* predsh = (float*)&A[0][0];   // [64 rows][2 wc]
    if (lr == 0) {
#pragma unroll
        for (int m = 0; m < 2; ++m)
#pragma unroll
            for (int j = 0; j < 4; ++j) {
                int row = ar0 + m * 16 + 4 * kg + j;
                predsh[row * 2 + wc] = pred[m][j];
            }
    }
    __syncthreads();
    if (tid < 64) {
        int row = tid;
        if (g0 + row < G)
            out[(size_t)(g0 + row) * T + t] = predsh[row * 2 + 0] + predsh[row * 2 + 1] + ob2[t];
    }
}

extern "C" void kernel_launch(void* const* d_in, const int* in_sizes, int n_in,
                              void* d_out, int out_size, void* d_ws, size_t ws_size,
                              hipStream_t stream) {
    const float* node_feats = (const float*)d_in[0];
    const int*   seg        = (const int*)d_in[1];
    const float* atom_w     = (const float*)d_in[3];
    const float* atom_b     = (const float*)d_in[4];
    const float* W1  = (const float*)d_in[5];
    const float* b1  = (const float*)d_in[6];
    const float* g1  = (const float*)d_in[7];
    const float* be1 = (const float*)d_in[8];
    const float* rm1 = (const float*)d_in[9];
    const float* rv1 = (const float*)d_in[10];
    const float* W2  = (const float*)d_in[11];
    const float* b2  = (const float*)d_in[12];
    const float* g2  = (const float*)d_in[13];
    const float* be2 = (const float*)d_in[14];
    const float* rm2 = (const float*)d_in[15];
    const float* rv2 = (const float*)d_in[16];
    const float* W3  = (const float*)d_in[17];
    const float* b3  = (const float*)d_in[18];
    const float* g3  = (const float*)d_in[19];
    const float* be3 = (const float*)d_in[20];
    const float* rm3 = (const float*)d_in[21];
    const float* rv3 = (const float*)d_in[22];
    const float* oW1 = (const float*)d_in[23];
    const float* ob1 = (const float*)d_in[24];
    const float* oW2 = (const float*)d_in[25];
    const float* ob2 = (const float*)d_in[26];

    int T = in_sizes[4];          // 12
    int F = in_sizes[3] / T;      // 128
    int N = in_sizes[0] / F;      // 1,000,000
    int G = out_size / T;         // 50,000

    char* ws = (char*)d_ws;
    size_t off = 0;
    int* start = (int*)ws;
    off += (((size_t)(G + 1) * 4) + 255) & ~(size_t)255;
    f16* Wt = (f16*)(ws + off);
    off += (((size_t)4 * T * 128 * 128 * 2) + 255) & ~(size_t)255;
    float* bp = (float*)(ws + off);
    off += (((size_t)4 * T * 128 * 4) + 255) & ~(size_t)255;
    f16* mol = (f16*)(ws + off);

    seg_starts_k<<<(N + 255) / 256, 256, 0, stream>>>(seg, N, G, start);
    prep_k<<<dim3(T, 4), 128, 0, stream>>>(W1, b1, W2, b2, W3, b3, oW1, ob1,
                                           g1, be1, rm1, rv1,
                                           g2, be2, rm2, rv2,
                                           g3, be3, rm3, rv3, Wt, bp);
    pool5_k<<<(G + 3) / 4, 256, 0, stream>>>(node_feats, atom_w, atom_b, start, mol, G);
    fc_k<<<dim3((G + 63) / 64, T), 256, 0, stream>>>(mol, Wt, bp, oW2, ob2,
                                                     (float*)d_out, G, T);
}

// Round 18
// 331.558 us; speedup vs baseline: 1.0130x; 1.0130x over previous
//
#include <hip/hip_runtime.h>
#include <hip/hip_bf16.h>
#include <hip/hip_fp16.h>

typedef _Float16 f16;
typedef _Float16 f16x2 __attribute__((ext_vector_type(2)));
typedef _Float16 f16x4 __attribute__((ext_vector_type(4)));
typedef _Float16 f16x8 __attribute__((ext_vector_type(8)));
typedef float f32x4 __attribute__((ext_vector_type(4)));

typedef __attribute__((address_space(1))) const void gas_t;
typedef __attribute__((address_space(3))) void las_t;

#define BN_EPS 1e-5f

// ---------------- kernel 1: graph start offsets from sorted segment_ids ----------------
__global__ void seg_starts_k(const int* __restrict__ seg, int N, int G, int* __restrict__ start) {
    int n = blockIdx.x * blockDim.x + threadIdx.x;
    if (n >= N) return;
    int s = seg[n];
    int p = (n == 0) ? -1 : seg[n - 1];
    for (int g = p + 1; g <= s; ++g) start[g] = n;
    if (n == N - 1) {
        for (int g = s + 1; g <= G; ++g) start[g] = N;
    }
}

// ---------------- kernel 2: weight prep (BN folding, fp16, PRE-SWIZZLED) ----------------
__global__ void prep_k(const float* __restrict__ W1, const float* __restrict__ b1,
                       const float* __restrict__ W2, const float* __restrict__ b2,
                       const float* __restrict__ W3, const float* __restrict__ b3,
                       const float* __restrict__ oW1, const float* __restrict__ ob1,
                       const float* __restrict__ g1, const float* __restrict__ be1,
                       const float* __restrict__ rm1, const float* __restrict__ rv1,
                       const float* __restrict__ g2, const float* __restrict__ be2,
                       const float* __restrict__ rm2, const float* __restrict__ rv2,
                       const float* __restrict__ g3, const float* __restrict__ be3,
                       const float* __restrict__ rm3, const float* __restrict__ rv3,
                       f16* __restrict__ Wt, float* __restrict__ bp) {
    int T = gridDim.x;
    int t = blockIdx.x, l = blockIdx.y;
    int o = threadIdx.x;  // 0..127
    __shared__ float s_sh[128], c_sh[128];

    const float *W, *b, *gg = nullptr, *be = nullptr, *rm = nullptr, *rv = nullptr;
    if (l == 0)      { W = W1;  b = b1; }
    else if (l == 1) { W = W2;  b = b2;  gg = g1; be = be1; rm = rm1; rv = rv1; }
    else if (l == 2) { W = W3;  b = b3;  gg = g2; be = be2; rm = rm2; rv = rv2; }
    else             { W = oW1; b = ob1; gg = g3; be = be3; rm = rm3; rv = rv3; }

    float s = 1.f, c = 0.f;
    if (gg) {
        float sv = gg[t * 128 + o] * rsqrtf(rv[t * 128 + o] + BN_EPS);
        s = sv;
        c = be[t * 128 + o] - rm[t * 128 + o] * sv;
    }
    s_sh[o] = s;
    c_sh[o] = c;
    __syncthreads();

    const float* Wsrc = W + (size_t)t * 128 * 128;
    f16* Wdst = Wt + (((size_t)l * T + t) * 128 + o) * 128;  // row o, swizzled cols
    float acc = b[t * 128 + o];
    for (int i = 0; i < 128; ++i) {
        float wv = Wsrc[i * 128 + o];
        Wdst[(((i >> 3) ^ (o & 7)) << 3) + (i & 7)] = (f16)(s_sh[i] * wv);
        acc += c_sh[i] * wv;
    }
    bp[((size_t)l * T + t) * 128 + o] = acc;
}

// ---------------- kernel 3: zero-LDS pooling + LDS-bounce store epilogue (pool5b) ----------------
// Compute path byte-identical to r10/r15 pool5. Epilogue: stage the wave's
// 12x128 f16 output (swizzle baked in) into wave-private LDS, then 3
// global_store_dwordx4 per lane (12 full 256B rows; ~48 store segments/wave
// vs 768 for the old 384 scalar u16 stores).
__global__ __launch_bounds__(256) void pool5_k(const float* __restrict__ feats,
                                               const float* __restrict__ atom_w,
                                               const float* __restrict__ atom_b,
                                               const int* __restrict__ start,
                                               f16* __restrict__ mol, int G) {
    __shared__ f16 wls_all[4][12][128];   // 3KB per wave, wave-private
    int wave = threadIdx.x >> 6, lane = threadIdx.x & 63;
    int g = blockIdx.x * 4 + wave;
    if (g >= G) return;
    int lr = lane & 15, kg = lane >> 4;
    f16 (*wls)[128] = wls_all[wave];

    f16x8 bfr[4];
    float ab = 0.f;
#pragma unroll
    for (int ks = 0; ks < 4; ++ks) {
        f16x8 v = {};
        if (lr < 12) {
            const float* s = atom_w + lr * 128 + ks * 32 + kg * 8;
#pragma unroll
            for (int j = 0; j < 8; ++j) v[j] = (f16)s[j];
        }
        bfr[ks] = v;
    }
    if (lr < 12) ab = atom_b[lr];

    f32x4 acc[8];
#pragma unroll
    for (int nf = 0; nf < 8; ++nf) acc[nf] = (f32x4){0.f, 0.f, 0.f, 0.f};

    int s = start[g], e = start[g + 1];

    for (int c0 = s; c0 < e; c0 += 16) {
        int rB[4];
#pragma unroll
        for (int j = 0; j < 4; ++j) {
            int a = c0 + (kg << 2) + j;
            rB[j] = (a < e) ? a : (e - 1);
        }
        float bx[8][4];
#pragma unroll
        for (int j = 0; j < 4; ++j) {
            const float* pB = feats + (size_t)rB[j] * 128 + lr;
#pragma unroll
            for (int fb = 0; fb < 8; ++fb) bx[fb][j] = pB[fb << 4];
        }

        int rA = c0 + lr; if (rA >= e) rA = e - 1;
        const float* pA = feats + (size_t)rA * 128 + (kg << 3);
        f32x4 pa = {0.f, 0.f, 0.f, 0.f};
#pragma unroll
        for (int ks = 0; ks < 4; ++ks) {
            float4 u0 = *(const float4*)(pA + (ks << 5));
            float4 u1 = *(const float4*)(pA + (ks << 5) + 4);
            f16x8 afr;
            afr[0] = (f16)u0.x; afr[1] = (f16)u0.y; afr[2] = (f16)u0.z; afr[3] = (f16)u0.w;
            afr[4] = (f16)u1.x; afr[5] = (f16)u1.y; afr[6] = (f16)u1.z; afr[7] = (f16)u1.w;
            pa = __builtin_amdgcn_mfma_f32_16x16x32_f16(afr, bfr[ks], pa, 0, 0, 0);
        }

        f16x4 a2;
#pragma unroll
        for (int j = 0; j < 4; ++j) {
            float w = 1.f / (1.f + __expf(-(pa[j] + ab)));
            int a = c0 + (kg << 2) + j;
            a2[j] = (a < e) ? (f16)w : (f16)0.f;
        }

#pragma unroll
        for (int fb = 0; fb < 8; ++fb) {
            f16x4 b2;
#pragma unroll
            for (int j = 0; j < 4; ++j) b2[j] = (f16)bx[fb][j];
            acc[fb] = __builtin_amdgcn_mfma_f32_16x16x16f16(a2, b2, acc[fb], 0, 0, 0);
        }
    }

    // epilogue: LDS bounce (swizzle baked in), then 3 b128 stores per lane
    if (kg < 3) {
        int gx = g & 7;
#pragma unroll
        for (int fb = 0; fb < 8; ++fb) {
            int slot = (fb << 1) + (lr >> 3);
            int fi = (((slot ^ gx)) << 3) + (lr & 7);
#pragma unroll
            for (int j = 0; j < 4; ++j)
                wls[(kg << 2) + j][fi] = (f16)acc[fb][j];
        }
    }
    // wave-private LDS; same-wave DS ordering -> no barrier needed
#pragma unroll
    for (int k = 0; k < 3; ++k) {
        int t = (k << 2) + kg;               // 0..11
        f16x8 v = *(const f16x8*)(&wls[t][lr << 3]);
        *(f16x8*)(mol + ((size_t)t * G + g) * 128 + (lr << 3)) = v;
    }
}

// ---------------- kernel 4: fc v3 — 2x2 wave tiling at 48KB, 3 blocks/CU ----------------
__global__ __launch_bounds__(256, 3) void fc_k(const f16* __restrict__ mol,
                                               const f16* __restrict__ Wt,
                                               const float* __restrict__ bp,
                                               const float* __restrict__ oW2,
                                               const float* __restrict__ ob2,
                                               float* __restrict__ out, int G, int T) {
    __shared__ f16 A[64][128];          // 16KB (aliased as pred scratch at end)
    __shared__ f16 B[128][128];         // 32KB

    int t = blockIdx.y;
    int g0 = blockIdx.x * 64;
    int tid = threadIdx.x;
    int wid = tid >> 6, lane = tid & 63;
    int kg = lane >> 4, lr = lane & 15;
    int wr = wid >> 1, wc = wid & 1;
    int ar0 = wr * 32, bc0 = wc * 64;

    {
        const f16* aplane = mol + (size_t)t * G * 128;
#pragma unroll
        for (int i = 0; i < 4; ++i) {
            int c = wid + (i << 2);                 // chunk 0..15
            int r = (c << 2) + kg;
            int row = g0 + r; if (row >= G) row = G - 1;
            const f16* src = aplane + (size_t)row * 128 + (lr << 3);
            __builtin_amdgcn_global_load_lds((gas_t*)src,
                (las_t*)((char*)&A[0][0] + c * 1024), 16, 0, 0);
        }
        const f16* bsrc = Wt + ((size_t)0 * T + t) * 16384;
#pragma unroll
        for (int i = 0; i < 8; ++i) {
            int c = wid + (i << 2);                 // chunk 0..31
            int r = (c << 2) + kg;
            const f16* src = bsrc + (size_t)r * 128 + (lr << 3);
            __builtin_amdgcn_global_load_lds((gas_t*)src,
                (las_t*)((char*)&B[0][0] + c * 1024), 16, 0, 0);
        }
    }

    float pred[2][4];
#pragma unroll
    for (int m = 0; m < 2; ++m)
#pragma unroll
        for (int j = 0; j < 4; ++j) pred[m][j] = 0.f;

    for (int l = 0; l < 4; ++l) {
        asm volatile("s_waitcnt vmcnt(0)" ::: "memory");   // B(l) (+prologue A) landed
        __syncthreads();                                   // bar1: staging + A(l-1) visible

        f16x8 afr[2][4];
#pragma unroll
        for (int m = 0; m < 2; ++m) {
            int row = ar0 + m * 16 + lr;
#pragma unroll
            for (int ks = 0; ks < 4; ++ks) {
                int sl = (4 * ks + kg) ^ (row & 7);
                afr[m][ks] = *(const f16x8*)(&A[row][sl * 8]);
            }
        }
        __syncthreads();    // bar2: afr reads done before cross-wave A-writeback

        const float* bias = bp + ((size_t)l * T + t) * 128;
#pragma unroll
        for (int n = 0; n < 4; ++n) {
            int col = bc0 + n * 16 + lr;
            f32x4 acc0 = {0.f, 0.f, 0.f, 0.f};
            f32x4 acc1 = {0.f, 0.f, 0.f, 0.f};
#pragma unroll
            for (int ks = 0; ks < 4; ++ks) {
                int sl = (4 * ks + kg) ^ (col & 7);
                f16x8 bfr = *(const f16x8*)(&B[col][sl * 8]);
                acc0 = __builtin_amdgcn_mfma_f32_16x16x32_f16(afr[0][ks], bfr, acc0, 0, 0, 0);
                acc1 = __builtin_amdgcn_mfma_f32_16x16x32_f16(afr[1][ks], bfr, acc1, 0, 0, 0);
            }
            float bv = bias[col];
            if (l < 3) {
#pragma unroll
                for (int j = 0; j < 4; ++j) {
                    float y0 = acc0[j] + bv; y0 = y0 > 0.f ? y0 : 0.f;
                    float y1 = acc1[j] + bv; y1 = y1 > 0.f ? y1 : 0.f;
                    int r0 = ar0 + 4 * kg + j;
                    int r1 = r0 + 16;
                    A[r0][(((col >> 3) ^ (r0 & 7)) << 3) + (col & 7)] = (f16)y0;
                    A[r1][(((col >> 3) ^ (r1 & 7)) << 3) + (col & 7)] = (f16)y1;
                }
            } else {
                float w2 = oW2[t * 128 + col];
#pragma unroll
                for (int j = 0; j < 4; ++j) {
                    float z0 = acc0[j] + bv; z0 = z0 > 0.f ? z0 : 0.f;
                    float z1 = acc1[j] + bv; z1 = z1 > 0.f ? z1 : 0.f;
                    pred[0][j] += z0 * w2;
                    pred[1][j] += z1 * w2;
                }
            }
        }
        __syncthreads();    // bar3: all waves done reading B(l)
        if (l < 3) {
            const f16* bsrc = Wt + ((size_t)(l + 1) * T + t) * 16384;
#pragma unroll
            for (int i = 0; i < 8; ++i) {
                int c = wid + (i << 2);
                int r = (c << 2) + kg;
                const f16* src = bsrc + (size_t)r * 128 + (lr << 3);
                __builtin_amdgcn_global_load_lds((gas_t*)src,
                    (las_t*)((char*)&B[0][0] + c * 1024), 16, 0, 0);
            }
        }
    }

#pragma unroll
    for (int msk = 1; msk < 16; msk <<= 1) {
#pragma unroll
        for (int m = 0; m < 2; ++m)
#pragma unroll
            for (int j = 0; j < 4; ++j)
                pred[m][j] += __shfl_xor(pred[m][j], msk, 64);
    }

    __syncthreads();
    float* predsh = (float*)&A[0][0];   // [64 rows][2 wc]
    if (lr == 0) {
#pragma unroll
        for (int m = 0; m < 2; ++m)
#pragma unroll
            for (int j = 0; j < 4; ++j) {
                int row = ar0 + m * 16 + 4 * kg + j;
                predsh[row * 2 + wc] = pred[m][j];
            }
    }
    __syncthreads();
    if (tid < 64) {
        int row = tid;
        if (g0 + row < G)
            out[(size_t)(g0 + row) * T + t] = predsh[row * 2 + 0] + predsh[row * 2 + 1] + ob2[t];
    }
}

extern "C" void kernel_launch(void* const* d_in, const int* in_sizes, int n_in,
                              void* d_out, int out_size, void* d_ws, size_t ws_size,
                              hipStream_t stream) {
    const float* node_feats = (const float*)d_in[0];
    const int*   seg        = (const int*)d_in[1];
    const float* atom_w     = (const float*)d_in[3];
    const float* atom_b     = (const float*)d_in[4];
    const float* W1  = (const float*)d_in[5];
    const float* b1  = (const float*)d_in[6];
    const float* g1  = (const float*)d_in[7];
    const float* be1 = (const float*)d_in[8];
    const float* rm1 = (const float*)d_in[9];
    const float* rv1 = (const float*)d_in[10];
    const float* W2  = (const float*)d_in[11];
    const float* b2  = (const float*)d_in[12];
    const float* g2  = (const float*)d_in[13];
    const float* be2 = (const float*)d_in[14];
    const float* rm2 = (const float*)d_in[15];
    const float* rv2 = (const float*)d_in[16];
    const float* W3  = (const float*)d_in[17];
    const float* b3  = (const float*)d_in[18];
    const float* g3  = (const float*)d_in[19];
    const float* be3 = (const float*)d_in[20];
    const float* rm3 = (const float*)d_in[21];
    const float* rv3 = (const float*)d_in[22];
    const float* oW1 = (const float*)d_in[23];
    const float* ob1 = (const float*)d_in[24];
    const float* oW2 = (const float*)d_in[25];
    const float* ob2 = (const float*)d_in[26];

    int T = in_sizes[4];          // 12
    int F = in_sizes[3] / T;      // 128
    int N = in_sizes[0] / F;      // 1,000,000
    int G = out_size / T;         // 50,000

    char* ws = (char*)d_ws;
    size_t off = 0;
    int* start = (int*)ws;
    off += (((size_t)(G + 1) * 4) + 255) & ~(size_t)255;
    f16* Wt = (f16*)(ws + off);
    off += (((size_t)4 * T * 128 * 128 * 2) + 255) & ~(size_t)255;
    float* bp = (float*)(ws + off);
    off += (((size_t)4 * T * 128 * 4) + 255) & ~(size_t)255;
    f16* mol = (f16*)(ws + off);

    seg_starts_k<<<(N + 255) / 256, 256, 0, stream>>>(seg, N, G, start);
    prep_k<<<dim3(T, 4), 128, 0, stream>>>(W1, b1, W2, b2, W3, b3, oW1, ob1,
                                           g1, be1, rm1, rv1,
                                           g2, be2, rm2, rv2,
                                           g3, be3, rm3, rv3, Wt, bp);
    pool5_k<<<(G + 3) / 4, 256, 0, stream>>>(node_feats, atom_w, atom_b, start, mol, G);
    fc_k<<<dim3((G + 63) / 64, T), 256, 0, stream>>>(mol, Wt, bp, oW2, ob2,
                                                     (float*)d_out, G, T);
}